// Round 1
// baseline (245.466 us; speedup 1.0000x reference)
//
#include <hip/hip_runtime.h>

// VQ-VAE forward (ConditionalVectorQuantizer): N=131072 rows of D=64, K=512 codes.
// Outputs (flat concat): [loss(1) | quantized_st(8388608, NCHW) | perplexity(1) | encodings(131072x512)]
//
// Design:
//  - wave = one (b,h) pair; lane = w. Row n = wid*64 + lane. Input/quantized accesses
//    are coalesced per channel c (lanes span w). Encodings slab per wave is contiguous 128KB.
//  - x row (64 f32) held in VGPRs; embedding rows are wave-uniform -> s_load (SGPR broadcast).
//  - distance = (||x||^2 + ||e_k||^2) - 2*dot  in the reference's f32 op order; strict < scan
//    reproduces jnp.argmin first-occurrence tie-break.
//  - 256MB encodings zero-fill is paced INSIDE the k-loop (1 store / 2 iters) so the write
//    drains under the compute; s_waitcnt vmcnt(0) orders the final one-hot scatter after it.
//  - loss accumulated in deterministic fixed point (2^20), counts via u32 atomics.

#define NE 512
#define ED 64
#define OFF_Q    1
#define OFF_PERP 8388609
#define OFF_ENC  8388610

__global__ __launch_bounds__(512) void vq_prep(const float* __restrict__ emb,
                                               float* __restrict__ Bk,
                                               unsigned* __restrict__ counts,
                                               unsigned long long* __restrict__ lossAcc) {
    int k = threadIdx.x;  // 512 threads, one per code
    const float4* e4 = reinterpret_cast<const float4*>(emb) + k * 16;
    float s = 0.f;
    #pragma unroll
    for (int i = 0; i < 16; ++i) {
        float4 v = e4[i];
        s += v.x * v.x + v.y * v.y + v.z * v.z + v.w * v.w;
    }
    Bk[k] = s;
    counts[k] = 0u;
    if (k == 0) *lossAcc = 0ull;
}

__global__ __launch_bounds__(256) void vq_main(const float* __restrict__ in,
                                               const float* __restrict__ emb,
                                               const float* __restrict__ Bk,
                                               unsigned* __restrict__ counts,
                                               unsigned long long* __restrict__ lossAcc,
                                               float* __restrict__ out) {
    const int wid  = (int)blockIdx.x * 4 + ((int)threadIdx.x >> 6);  // 0..2047 = b*64+h
    const int lane = (int)threadIdx.x & 63;                          // = w
    const int bb = wid >> 6;
    const int hh = wid & 63;
    const size_t inBase = (size_t)bb * 262144 + (size_t)hh * 64 + (size_t)lane;

    // Load this lane's row: x[c] = inputs[b, c, h, w]; coalesced across lanes per c.
    float x[64];
    #pragma unroll
    for (int c = 0; c < 64; ++c) x[c] = in[inBase + (size_t)c * 4096];

    // ||x||^2 (4 partials for ILP)
    float a0 = 0.f, a1 = 0.f, a2 = 0.f, a3 = 0.f;
    #pragma unroll
    for (int c = 0; c < 64; c += 4) {
        a0 += x[c] * x[c];
        a1 += x[c + 1] * x[c + 1];
        a2 += x[c + 2] * x[c + 2];
        a3 += x[c + 3] * x[c + 3];
    }
    const float A = (a0 + a1) + (a2 + a3);

    // Encodings slab for this wave: rows [wid*64, wid*64+64), contiguous 32768 floats.
    // base byte offset is 8-aligned (not 16) -> float2 stores.
    float2* enc2 = reinterpret_cast<float2*>(out + OFF_ENC + (size_t)wid * 32768);
    const float2 z2 = make_float2(0.f, 0.f);

    float bestd = 3.4e38f;
    int bestk = 0;

    // k-loop: 2 codes per iteration + 1 paced zero-fill store (256 stores over 256 iters).
    for (int kk = 0; kk < 256; ++kk) {
        enc2[kk * 64 + lane] = z2;  // paced zero-fill, drains under compute

        #pragma unroll
        for (int u = 0; u < 2; ++u) {
            const int k = kk * 2 + u;
            const float* __restrict__ e = emb + k * 64;  // wave-uniform -> s_load
            float c0 = 0.f, c1 = 0.f, c2 = 0.f, c3 = 0.f;
            #pragma unroll
            for (int d = 0; d < 64; d += 4) {
                c0 += x[d]     * e[d];
                c1 += x[d + 1] * e[d + 1];
                c2 += x[d + 2] * e[d + 2];
                c3 += x[d + 3] * e[d + 3];
            }
            float dot  = (c0 + c1) + (c2 + c3);
            float dist = (A + Bk[k]) - 2.0f * dot;   // reference op order
            if (dist < bestd) { bestd = dist; bestk = k; }  // strict < = first-min
        }
    }

    atomicAdd(&counts[bestk], 1u);

    // Gather chosen code (per-lane divergent, L1/L2-resident 128KB table),
    // write quantized_st = x + (q - x) in NCHW, accumulate loss sum (q - x)^2.
    const float* __restrict__ eq = emb + bestk * 64;
    float l0 = 0.f, l1 = 0.f, l2 = 0.f, l3 = 0.f;
    #pragma unroll
    for (int c = 0; c < 64; c += 4) {
        float q0 = eq[c], q1 = eq[c + 1], q2 = eq[c + 2], q3 = eq[c + 3];
        float d0 = q0 - x[c],     d1 = q1 - x[c + 1];
        float d2 = q2 - x[c + 2], d3 = q3 - x[c + 3];
        l0 += d0 * d0; l1 += d1 * d1; l2 += d2 * d2; l3 += d3 * d3;
        out[OFF_Q + inBase + (size_t)c * 4096]       = x[c]     + d0;
        out[OFF_Q + inBase + (size_t)(c + 1) * 4096] = x[c + 1] + d1;
        out[OFF_Q + inBase + (size_t)(c + 2) * 4096] = x[c + 2] + d2;
        out[OFF_Q + inBase + (size_t)(c + 3) * 4096] = x[c + 3] + d3;
    }
    float lsum = (l0 + l1) + (l2 + l3);
    #pragma unroll
    for (int off = 32; off > 0; off >>= 1) lsum += __shfl_down(lsum, off);
    if (lane == 0) {
        unsigned long long fx = (unsigned long long)((double)lsum * 1048576.0);
        atomicAdd(lossAcc, fx);
    }

    // Ensure the zero-fill stores have completed, then scatter the one-hot 1.0s.
    asm volatile("s_waitcnt vmcnt(0)" ::: "memory");
    out[OFF_ENC + (size_t)wid * 32768 + (size_t)lane * 512 + (size_t)bestk] = 1.0f;
}

__global__ __launch_bounds__(512) void vq_fin(const unsigned* __restrict__ counts,
                                              const unsigned long long* __restrict__ lossAcc,
                                              float* __restrict__ out) {
    __shared__ float red[512];
    int k = threadIdx.x;
    float p = (float)counts[k] * (1.0f / 131072.0f);  // exact: count * 2^-17
    red[k] = p * logf(p + 1e-10f);
    __syncthreads();
    for (int s = 256; s > 0; s >>= 1) {
        if (k < s) red[k] += red[k + s];
        __syncthreads();
    }
    if (k == 0) {
        out[OFF_PERP] = expf(-red[0]);
        double m = ((double)(*lossAcc) / 1048576.0) / 8388608.0;
        float mf = (float)m;
        out[0] = mf + 0.25f * mf;  // q_latent + 0.25 * e_latent (identical values)
    }
}

extern "C" void kernel_launch(void* const* d_in, const int* in_sizes, int n_in,
                              void* d_out, int out_size, void* d_ws, size_t ws_size,
                              hipStream_t stream) {
    const float* in  = (const float*)d_in[0];
    // d_in[1] = labels (unused by the reference forward)
    const float* emb = (const float*)d_in[2];
    float* out = (float*)d_out;

    float* Bk                    = (float*)d_ws;                              // 512 f32
    unsigned* counts             = (unsigned*)((char*)d_ws + 2048);           // 512 u32
    unsigned long long* lossAcc  = (unsigned long long*)((char*)d_ws + 4096); // 1 u64

    vq_prep<<<1, 512, 0, stream>>>(emb, Bk, counts, lossAcc);
    vq_main<<<512, 256, 0, stream>>>(in, emb, Bk, counts, lossAcc, out);
    vq_fin<<<1, 512, 0, stream>>>(counts, lossAcc, out);
}